// Round 1
// 380.884 us; speedup vs baseline: 1.0698x; 1.0698x over previous
//
#include <hip/hip_runtime.h>

typedef unsigned short u16;
typedef unsigned int u32;

#define D_DIM 128
#define CHUNK 4096   // elements scanned per block (256 threads x 16)

typedef __attribute__((ext_vector_type(8))) short bf16x8;
typedef __attribute__((ext_vector_type(4))) float f32x4;

__device__ __forceinline__ float bf2f(u16 h) {
    u32 u = ((u32)h) << 16;
    return __uint_as_float(u);
}
__device__ __forceinline__ u16 f2bf(float f) {
    u32 u = __float_as_uint(f);
    u32 r = (u >> 16) & 1u;
    u += 0x7fffu + r;                 // round-to-nearest-even
    return (u16)(u >> 16);
}
__device__ __forceinline__ float lo16(u32 u) { return bf2f((u16)(u & 0xffffu)); }
__device__ __forceinline__ float hi16(u32 u) { return bf2f((u16)(u >> 16)); }

// --- K0: dtype detector (bf16 vs fp32 packing of the float tensors) ---------
__global__ void k_detect(const u32* w, int* flag) {
    __shared__ int cnt;
    if (threadIdx.x == 0) cnt = 0;
    __syncthreads();
    int c = 0;
    for (int j = 0; j < 4; ++j) {
        u32 x = w[threadIdx.x * 4 + j];
        u32 e = (x >> 7) & 0xFFu;
        if (e >= 100u && e <= 140u) c++;
    }
    atomicAdd(&cnt, c);
    __syncthreads();
    if (threadIdx.x == 0) flag[0] = (cnt >= 700) ? 1 : 0;
}

// --- K1: zero scratch words (harness's expected symbol name kept) -----------
__global__ void GCNLayer_76647986365164_kernel(int* p, int nwords) {
    int i = blockIdx.x * blockDim.x + threadIdx.x;
    if (i < nwords) p[i] = 0;
}

// --- K2: in-degree count ----------------------------------------------------
__global__ void k_deg(const int* dst, int* deg, int E) {
    int i = blockIdx.x * blockDim.x + threadIdx.x;
    if (i < E) atomicAdd(&deg[dst[i]], 1);
}

// --- K3a: block-local exclusive scan (multi-block; LDS Hillis-Steele) -------
__global__ void k_scan_local(const int* deg, int* offs, int* bsums, int n) {
    __shared__ int tsum[256];
    const int tid = threadIdx.x;
    const int base = blockIdx.x * CHUNK + tid * 16;
    int v[16];
    int run = 0;
    for (int j = 0; j < 16; ++j) {
        int idx = base + j;
        v[j] = (idx < n) ? deg[idx] : 0;
        run += v[j];
    }
    tsum[tid] = run;
    __syncthreads();
    for (int off = 1; off < 256; off <<= 1) {      // inclusive scan of thread sums
        int val = tsum[tid];
        int add = (tid >= off) ? tsum[tid - off] : 0;
        __syncthreads();
        tsum[tid] = val + add;
        __syncthreads();
    }
    int acc = tsum[tid] - run;                     // exclusive start (local)
    for (int j = 0; j < 16; ++j) {
        int idx = base + j;
        if (idx < n) offs[idx] = acc;
        acc += v[j];
    }
    if (tid == 255) bsums[blockIdx.x] = tsum[255];
}

// --- K3b: add scanned block totals; emit final offs + cursor ----------------
__global__ void k_scan_add(int* offs, int* cursor, const int* bsums,
                           int n, int nblk) {
    __shared__ int carry_s;
    const int tid = threadIdx.x;
    const int b = blockIdx.x;
    if (tid == 0) {
        int c = 0;
        for (int i = 0; i < b; ++i) c += bsums[i];
        carry_s = c;
        if (b == nblk - 1) offs[n] = c + bsums[b];   // total == E
    }
    __syncthreads();
    const int carry = carry_s;
    const int base = b * CHUNK + tid * 16;
    for (int j = 0; j < 16; ++j) {
        int idx = base + j;
        if (idx < n) {
            int val = offs[idx] + carry;
            offs[idx] = val;
            cursor[idx] = val;
        }
    }
}

// --- K4: scatter edges into CSR buckets -------------------------------------
__global__ void k_scatter(const int* src, const int* dst,
                          int* cursor, int* csr, int E) {
    int i = blockIdx.x * blockDim.x + threadIdx.x;
    if (i < E) {
        int d = dst[i];
        int pos = atomicAdd(&cursor[d], 1);
        csr[pos] = src[i];
    }
}

// --- K5: gather-reduce mean aggregation, one wave per node ------------------
// Latency-bound fix: 16B/lane loads. One uint4 load instruction fetches FOUR
// 256B feature rows (lane group g=lane>>4 owns edge slot j+g/j+g+4/..., lane
// chunk c=lane&15 owns 16B of the row). 4 loads (16 edges) in flight per
// iteration vs the old 2x 4B-per-lane pipeline (~8x bytes in flight/wave).
// Per-lane partial column sums are combined with two shfl_xor steps at the end.
__global__ void k_aggregate(const void* feature, const int* offs,
                            const int* csr, u16* agg, const int* flag,
                            int n, int npad) {
    int node = blockIdx.x * 4 + (threadIdx.x >> 6);
    int lane = threadIdx.x & 63;
    if (node >= npad) return;
    const int g = lane >> 4;       // edge sub-slot 0..3
    const int c = lane & 15;       // 16B chunk (8 bf16 cols) within row
    int bf = flag[0];
    float acc[8];
    #pragma unroll
    for (int t = 0; t < 8; ++t) acc[t] = 0.f;
    int degn = 0;
    if (node < n) {
        int s = offs[node], e = offs[node + 1];
        degn = e - s;
        if (bf) {
            const uint4* fq = (const uint4*)feature;   // row = 16 uint4
            for (int j = s; j < e; j += 16) {
                int j0 = j + g, j1 = j0 + 4, j2 = j0 + 8, j3 = j0 + 12;
                uint4 u0 = {0,0,0,0}, u1 = {0,0,0,0}, u2 = {0,0,0,0}, u3 = {0,0,0,0};
                if (j0 < e) u0 = fq[(size_t)csr[j0] * 16 + c];
                if (j1 < e) u1 = fq[(size_t)csr[j1] * 16 + c];
                if (j2 < e) u2 = fq[(size_t)csr[j2] * 16 + c];
                if (j3 < e) u3 = fq[(size_t)csr[j3] * 16 + c];
                #define ACC8(U) \
                    acc[0] += lo16(U.x); acc[1] += hi16(U.x); \
                    acc[2] += lo16(U.y); acc[3] += hi16(U.y); \
                    acc[4] += lo16(U.z); acc[5] += hi16(U.z); \
                    acc[6] += lo16(U.w); acc[7] += hi16(U.w);
                ACC8(u0); ACC8(u1); ACC8(u2); ACC8(u3);
                #undef ACC8
            }
        } else {
            const float4* fq = (const float4*)feature;  // row = 32 float4
            for (int j = s; j < e; j += 8) {
                int j0 = j + g, j1 = j0 + 4;
                if (j0 < e) {
                    size_t b0 = (size_t)csr[j0] * 32 + c * 2;
                    float4 x = fq[b0], y = fq[b0 + 1];
                    acc[0] += x.x; acc[1] += x.y; acc[2] += x.z; acc[3] += x.w;
                    acc[4] += y.x; acc[5] += y.y; acc[6] += y.z; acc[7] += y.w;
                }
                if (j1 < e) {
                    size_t b1 = (size_t)csr[j1] * 32 + c * 2;
                    float4 x = fq[b1], y = fq[b1 + 1];
                    acc[0] += x.x; acc[1] += x.y; acc[2] += x.z; acc[3] += x.w;
                    acc[4] += y.x; acc[5] += y.y; acc[6] += y.z; acc[7] += y.w;
                }
            }
        }
    }
    // combine the 4 edge-slot partials (lanes g=0..3 share chunk c)
    #pragma unroll
    for (int t = 0; t < 8; ++t) {
        acc[t] += __shfl_xor(acc[t], 16);
        acc[t] += __shfl_xor(acc[t], 32);
    }
    float sc = 1.0f / (float)(degn > 1 ? degn : 1);
    if (g == 0) {
        uint4 o4;
        o4.x = (u32)f2bf(acc[0] * sc) | ((u32)f2bf(acc[1] * sc) << 16);
        o4.y = (u32)f2bf(acc[2] * sc) | ((u32)f2bf(acc[3] * sc) << 16);
        o4.z = (u32)f2bf(acc[4] * sc) | ((u32)f2bf(acc[5] * sc) << 16);
        o4.w = (u32)f2bf(acc[6] * sc) | ((u32)f2bf(acc[7] * sc) << 16);
        ((uint4*)(agg + (size_t)node * D_DIM))[c] = o4;
    }
}

// --- K6: h = agg @ W^T + b via bf16 MFMA, h written IN PLACE over agg -------
// Block = 64 rows x 128 cols, 4 waves, each wave one 16-row strip.
// A-frag (16x32): lane reads agg[rb+w*16+(l&15)][kt*32+(l>>4)*8 ..+7] straight
// from global (16B contiguous). B-frag = W^T: lane reads W[ot*16+(l&15)][...]
// from LDS-staged W (row pad 136 u16 -> 2-way-max bank spread on b128 reads).
// fp32-W path: two MFMA passes with W split into bf16 hi + lo planes, so GEMM
// precision stays dominated by agg's existing bf16 rounding.
__global__ void k_gemm(u16* agg, const void* W, const void* bias,
                       float* colsum, float* colsq, const int* flag, int n) {
    __shared__ u16 sW[128 * 136];
    __shared__ float bsum[128], bsq[128];
    const int tid = threadIdx.x;
    const int rb = blockIdx.x * 64;
    const int bf = flag[0];
    const int w = tid >> 6;
    const int lane = tid & 63;
    const int g = lane >> 4, c = lane & 15;

    if (tid < 128) { bsum[tid] = 0.f; bsq[tid] = 0.f; }

    // A fragments: 4 x 16B per lane, reused across all 8 output tiles + passes
    bf16x8 afr[4];
    {
        const u16* arow = agg + (size_t)(rb + w * 16 + c) * D_DIM + g * 8;
        #pragma unroll
        for (int kt = 0; kt < 4; ++kt)
            afr[kt] = *(const bf16x8*)(arow + kt * 32);
    }

    f32x4 acc[8];
    #pragma unroll
    for (int ot = 0; ot < 8; ++ot) acc[ot] = (f32x4){0.f, 0.f, 0.f, 0.f};

    const int npass = bf ? 1 : 2;
    for (int pass = 0; pass < npass; ++pass) {
        if (bf) {
            #pragma unroll
            for (int i = 0; i < 8; ++i) {
                int e = (i * 256 + tid) * 8;
                int row = e >> 7, k = e & 127;
                *(uint4*)(&sW[row * 136 + k]) = *(const uint4*)((const u16*)W + e);
            }
        } else {
            const float* Wf = (const float*)W;
            #pragma unroll
            for (int i = 0; i < 8; ++i) {
                int e = (i * 256 + tid) * 8;
                int row = e >> 7, k = e & 127;
                float4 x = *(const float4*)(Wf + e);
                float4 y = *(const float4*)(Wf + e + 4);
                float v[8] = {x.x, x.y, x.z, x.w, y.x, y.y, y.z, y.w};
                u16 hb[8];
                #pragma unroll
                for (int j = 0; j < 8; ++j) {
                    u16 h = f2bf(v[j]);
                    if (pass == 1) h = f2bf(v[j] - bf2f(h));   // residual plane
                    hb[j] = h;
                }
                uint4 pk;
                pk.x = (u32)hb[0] | ((u32)hb[1] << 16);
                pk.y = (u32)hb[2] | ((u32)hb[3] << 16);
                pk.z = (u32)hb[4] | ((u32)hb[5] << 16);
                pk.w = (u32)hb[6] | ((u32)hb[7] << 16);
                *(uint4*)(&sW[row * 136 + k]) = pk;
            }
        }
        __syncthreads();
        #pragma unroll
        for (int ot = 0; ot < 8; ++ot) {
            const u16* wrow = &sW[(ot * 16 + c) * 136 + g * 8];
            #pragma unroll
            for (int kt = 0; kt < 4; ++kt) {
                bf16x8 bfr = *(const bf16x8*)(wrow + kt * 32);
                acc[ot] = __builtin_amdgcn_mfma_f32_16x16x32_bf16(
                    afr[kt], bfr, acc[ot], 0, 0, 0);
            }
        }
        if (pass + 1 < npass) __syncthreads();   // before restaging W plane
    }

    // Epilogue: bias, BN partial stats (rows<n only), packed bf16 store.
    // D layout: col = ot*16 + (lane&15), row-in-strip = (lane>>4)*4 + r.
    const int rowbase = rb + w * 16 + g * 4;
    #pragma unroll
    for (int ot = 0; ot < 8; ++ot) {
        const int o = ot * 16 + c;
        float bv = bf ? bf2f(((const u16*)bias)[o]) : ((const float*)bias)[o];
        float s = 0.f, q = 0.f;
        float hv[4];
        #pragma unroll
        for (int r = 0; r < 4; ++r) {
            float h = acc[ot][r] + bv;
            hv[r] = h;
            if (rowbase + r < n) { s += h; q += h * h; }
        }
        #pragma unroll
        for (int r = 0; r < 4; ++r) {
            float hp = __shfl_xor(hv[r], 1);       // neighbor col (o^1)
            if (!(lane & 1)) {
                u32 pk = (u32)f2bf(hv[r]) | ((u32)f2bf(hp) << 16);
                *(u32*)(agg + (size_t)(rowbase + r) * D_DIM + o) = pk;
            }
        }
        s += __shfl_xor(s, 16); s += __shfl_xor(s, 32);
        q += __shfl_xor(q, 16); q += __shfl_xor(q, 32);
        if (g == 0) { atomicAdd(&bsum[o], s); atomicAdd(&bsq[o], q); }
    }
    __syncthreads();
    if (tid < 128) {
        atomicAdd(&colsum[tid], bsum[tid]);
        atomicAdd(&colsq[tid], bsq[tid]);
    }
}

// --- K7: BN stats -> per-column scale/shift ---------------------------------
__global__ void k_finalize(const float* stats, const void* gamma,
                           const void* beta, float* scsh, const int* flag,
                           float invn) {
    int t = threadIdx.x;
    int bf = flag[0];
    if (t < 128) {
        float mean = stats[t] * invn;
        float var = stats[128 + t] * invn - mean * mean;
        var = fmaxf(var, 0.f);
        float inv = rsqrtf(var + 1e-5f);
        float g = bf ? bf2f(((const u16*)gamma)[t]) : ((const float*)gamma)[t];
        float bb = bf ? bf2f(((const u16*)beta)[t]) : ((const float*)beta)[t];
        float sc = inv * g;
        float sh = bb - mean * sc;
        scsh[t] = sc;
        scsh[128 + t] = sh;
    }
}

// --- K8: out = feature + relu(h*scale + shift), dual dtype ------------------
__global__ void k_apply(const u16* h, const void* feature, const float* scsh,
                        void* outp, const int* flag, int total8) {
    __shared__ float ssc[128], ssh[128];
    int tid = threadIdx.x;
    if (tid < 128) { ssc[tid] = scsh[tid]; ssh[tid] = scsh[128 + tid]; }
    __syncthreads();
    int i = blockIdx.x * 256 + tid;
    if (i >= total8) return;
    int bf = flag[0];
    size_t base = (size_t)i * 8;
    int c0 = (int)(base & (D_DIM - 1));
    uint4 h4 = ((const uint4*)h)[i];
    u32 hw[4] = {h4.x, h4.y, h4.z, h4.w};
    float hv[8];
    for (int j = 0; j < 4; ++j) { hv[2*j] = lo16(hw[j]); hv[2*j+1] = hi16(hw[j]); }
    float fv[8];
    if (bf) {
        uint4 f4 = ((const uint4*)feature)[i];
        u32 fw[4] = {f4.x, f4.y, f4.z, f4.w};
        for (int j = 0; j < 4; ++j) { fv[2*j] = lo16(fw[j]); fv[2*j+1] = hi16(fw[j]); }
    } else {
        float4 fa = ((const float4*)feature)[i * 2];
        float4 fb = ((const float4*)feature)[i * 2 + 1];
        fv[0]=fa.x; fv[1]=fa.y; fv[2]=fa.z; fv[3]=fa.w;
        fv[4]=fb.x; fv[5]=fb.y; fv[6]=fb.z; fv[7]=fb.w;
    }
    float ov[8];
    for (int j = 0; j < 8; ++j)
        ov[j] = fmaxf(hv[j] * ssc[c0 + j] + ssh[c0 + j], 0.f) + fv[j];
    if (bf) {
        uint4 o4;
        u32 ow[4];
        for (int j = 0; j < 4; ++j)
            ow[j] = (u32)f2bf(ov[2*j]) | ((u32)f2bf(ov[2*j+1]) << 16);
        o4.x = ow[0]; o4.y = ow[1]; o4.z = ow[2]; o4.w = ow[3];
        ((uint4*)outp)[i] = o4;
    } else {
        float4 oa, ob;
        oa.x=ov[0]; oa.y=ov[1]; oa.z=ov[2]; oa.w=ov[3];
        ob.x=ov[4]; ob.y=ov[5]; ob.z=ov[6]; ob.w=ov[7];
        ((float4*)outp)[i * 2] = oa;
        ((float4*)outp)[i * 2 + 1] = ob;
    }
}

static inline size_t al256s(size_t x) { return (x + 255) & ~(size_t)255; }
static inline int gmax1(int x) { return x > 0 ? x : 1; }

extern "C" void kernel_launch(void* const* d_in, const int* in_sizes, int n_in,
                              void* d_out, int out_size, void* d_ws, size_t ws_size,
                              hipStream_t stream) {
    const void* feature = d_in[0];
    const int*  src     = (const int*)d_in[1];
    const int*  dst     = (const int*)d_in[2];
    const void* W       = d_in[3];
    const void* bias    = d_in[4];
    const void* gamma   = d_in[5];
    const void* beta    = d_in[6];

    const int N = in_sizes[0] / D_DIM;
    const int E = in_sizes[1];
    const int Npad = (N + 63) & ~63;
    const int nblk = (N + CHUNK - 1) / CHUNK;      // scan blocks

    char* p = (char*)d_ws;
    size_t o = 0;
    int*   flag   = (int*)(p + o);      o += 256;
    int*   deg    = (int*)(p + o);      o += (size_t)N * 4;
    float* stats  = (float*)(p + o);    o += 256 * 4;           // sum[128],sq[128]
    const int zero_words = N + 256;                              // deg+stats contiguous
    o = al256s(o);
    float* scsh   = (float*)(p + o);    o += al256s(256 * 4);
    int*   bsums  = (int*)(p + o);      o += al256s(((size_t)nblk + 8) * 4);
    int*   offs   = (int*)(p + o);      o += al256s(((size_t)N + 8) * 4);
    int*   cursor = (int*)(p + o);      o += al256s(((size_t)N + 8) * 4);
    int*   csr    = (int*)(p + o);      o += al256s((size_t)E * 4);
    u16*   agg    = (u16*)(p + o);      o += al256s((size_t)Npad * D_DIM * 2);
    (void)ws_size; (void)n_in; (void)out_size;

    int eb = gmax1((E + 255) / 256);
    int total8 = N * D_DIM / 8;

    k_detect<<<1, 256, 0, stream>>>((const u32*)feature, flag);
    GCNLayer_76647986365164_kernel<<<gmax1((zero_words + 255) / 256), 256, 0, stream>>>(deg, zero_words);
    k_deg<<<eb, 256, 0, stream>>>(dst, deg, E);
    k_scan_local<<<gmax1(nblk), 256, 0, stream>>>(deg, offs, bsums, N);
    k_scan_add<<<gmax1(nblk), 256, 0, stream>>>(offs, cursor, bsums, N, nblk);
    k_scatter<<<eb, 256, 0, stream>>>(src, dst, cursor, csr, E);
    k_aggregate<<<gmax1(Npad / 4), 256, 0, stream>>>(feature, offs, csr, agg, flag, N, Npad);
    k_gemm<<<gmax1(Npad / 64), 256, 0, stream>>>(agg, W, bias, stats, stats + 128, flag, N);
    k_finalize<<<1, 128, 0, stream>>>(stats, gamma, beta, scsh, flag, 1.0f / (float)N);
    k_apply<<<gmax1((total8 + 255) / 256), 256, 0, stream>>>(agg, feature, scsh, d_out, flag, total8);
}

// Round 2
// 323.758 us; speedup vs baseline: 1.2586x; 1.1764x over previous
//
#include <hip/hip_runtime.h>

typedef unsigned short u16;
typedef unsigned int u32;

#define D_DIM 128
#define CHUNK 4096    // elements scanned per block (256 threads x 16)
#define SCHUNK 4096   // edges per scatter stripe
#define NPART 8       // XCD count

typedef __attribute__((ext_vector_type(8))) short bf16x8;
typedef __attribute__((ext_vector_type(4))) float f32x4;

__device__ __forceinline__ float bf2f(u16 h) {
    u32 u = ((u32)h) << 16;
    return __uint_as_float(u);
}
__device__ __forceinline__ u16 f2bf(float f) {
    u32 u = __float_as_uint(f);
    u32 r = (u >> 16) & 1u;
    u += 0x7fffu + r;                 // round-to-nearest-even
    return (u16)(u >> 16);
}
__device__ __forceinline__ float lo16(u32 u) { return bf2f((u16)(u & 0xffffu)); }
__device__ __forceinline__ float hi16(u32 u) { return bf2f((u16)(u >> 16)); }

// --- K1: zero scratch words + dtype detect (merged; harness symbol kept) ----
__global__ void GCNLayer_76647986365164_kernel(int* p, int nwords,
                                               const u32* w, int* flag) {
    int i = blockIdx.x * blockDim.x + threadIdx.x;
    if (i < nwords) p[i] = 0;
    if (blockIdx.x == 0) {
        __shared__ int cnt;
        if (threadIdx.x == 0) cnt = 0;
        __syncthreads();
        int c = 0;
        for (int j = 0; j < 4; ++j) {
            u32 x = w[threadIdx.x * 4 + j];
            u32 e = (x >> 7) & 0xFFu;
            if (e >= 100u && e <= 140u) c++;
        }
        atomicAdd(&cnt, c);
        __syncthreads();
        if (threadIdx.x == 0) flag[0] = (cnt >= 700) ? 1 : 0;
    }
}

// --- K2: in-degree count + per-edge bucket rank -----------------------------
// The atomic's return value IS the edge's rank within its dst bucket, making
// the scatter pass fully atomic-free (total atomic count across the pipeline
// halves vs the cursor scheme).
__global__ void k_deg(const int* __restrict__ dst, int* __restrict__ deg,
                      int* __restrict__ rank, int E) {
    int i = blockIdx.x * blockDim.x + threadIdx.x;
    if (i < E) rank[i] = atomicAdd(&deg[dst[i]], 1);
}

// --- K3a: block-local exclusive scan (multi-block; LDS Hillis-Steele) -------
__global__ void k_scan_local(const int* deg, int* offs, int* bsums, int n) {
    __shared__ int tsum[256];
    const int tid = threadIdx.x;
    const int base = blockIdx.x * CHUNK + tid * 16;
    int v[16];
    int run = 0;
    for (int j = 0; j < 16; ++j) {
        int idx = base + j;
        v[j] = (idx < n) ? deg[idx] : 0;
        run += v[j];
    }
    tsum[tid] = run;
    __syncthreads();
    for (int off = 1; off < 256; off <<= 1) {      // inclusive scan of thread sums
        int val = tsum[tid];
        int add = (tid >= off) ? tsum[tid - off] : 0;
        __syncthreads();
        tsum[tid] = val + add;
        __syncthreads();
    }
    int acc = tsum[tid] - run;                     // exclusive start (local)
    for (int j = 0; j < 16; ++j) {
        int idx = base + j;
        if (idx < n) offs[idx] = acc;
        acc += v[j];
    }
    if (tid == 255) bsums[blockIdx.x] = tsum[255];
}

// --- K3b: add scanned block totals; emit final offs -------------------------
__global__ void k_scan_add(int* offs, const int* bsums, int n, int nblk) {
    __shared__ int carry_s;
    const int tid = threadIdx.x;
    const int b = blockIdx.x;
    if (tid == 0) {
        int c = 0;
        for (int i = 0; i < b; ++i) c += bsums[i];
        carry_s = c;
        if (b == nblk - 1) offs[n] = c + bsums[b];   // total == E
    }
    __syncthreads();
    const int carry = carry_s;
    const int base = b * CHUNK + tid * 16;
    for (int j = 0; j < 16; ++j) {
        int idx = base + j;
        if (idx < n) offs[idx] += carry;
    }
}

// --- K4: scatter edges into CSR buckets, XCD-partitioned, atomic-free -------
// Old version: random 4B csr writes from all 8 XCDs -> every line evicted
// partial -> WRITE_SIZE 69.5 MB for a 4 MB payload, 1 TB/s, 75 us.
// New: grid = 8 partitions x stripes; block handles dst-partition (bid&7),
// which lands on XCD bid%8 under round-robin dispatch, so each csr line is
// written by ONE XCD's L2 and evicts once, full. pos = offs[d] + rank[i] is
// deterministic (no atomics). Correct regardless of the actual block->XCD
// mapping (coverage is by stripe x partition, not by placement).
__global__ void k_scatter(const int* __restrict__ src, const int* __restrict__ dst,
                          const int* __restrict__ rank, const int* __restrict__ offs,
                          int* __restrict__ csr, int E, int nper) {
    const int pr = blockIdx.x & (NPART - 1);
    const int s  = blockIdx.x >> 3;
    const int lo = pr * nper;
    const int hi = lo + nper;
    const int base = s * SCHUNK;
    int end = base + SCHUNK;
    if (end > E) end = E;
    for (int i = base + (int)threadIdx.x; i < end; i += 256) {
        int d = dst[i];
        if (d >= lo && d < hi) {
            csr[offs[d] + rank[i]] = src[i];
        }
    }
}

// --- K5: gather-reduce mean aggregation, one wave per node ------------------
// 16B/lane loads: one uint4 load instruction fetches FOUR 256B feature rows
// (lane group g=lane>>4 owns edge slot, lane chunk c=lane&15 owns 16B of the
// row); partial column sums combined with two shfl_xor steps at the end.
__global__ void k_aggregate(const void* feature, const int* offs,
                            const int* csr, u16* agg, const int* flag,
                            int n, int npad) {
    int node = blockIdx.x * 4 + (threadIdx.x >> 6);
    int lane = threadIdx.x & 63;
    if (node >= npad) return;
    const int g = lane >> 4;       // edge sub-slot 0..3
    const int c = lane & 15;       // 16B chunk (8 bf16 cols) within row
    int bf = flag[0];
    float acc[8];
    #pragma unroll
    for (int t = 0; t < 8; ++t) acc[t] = 0.f;
    int degn = 0;
    if (node < n) {
        int s = offs[node], e = offs[node + 1];
        degn = e - s;
        if (bf) {
            const uint4* fq = (const uint4*)feature;   // row = 16 uint4
            for (int j = s; j < e; j += 16) {
                int j0 = j + g, j1 = j0 + 4, j2 = j0 + 8, j3 = j0 + 12;
                uint4 u0 = {0,0,0,0}, u1 = {0,0,0,0}, u2 = {0,0,0,0}, u3 = {0,0,0,0};
                if (j0 < e) u0 = fq[(size_t)csr[j0] * 16 + c];
                if (j1 < e) u1 = fq[(size_t)csr[j1] * 16 + c];
                if (j2 < e) u2 = fq[(size_t)csr[j2] * 16 + c];
                if (j3 < e) u3 = fq[(size_t)csr[j3] * 16 + c];
                #define ACC8(U) \
                    acc[0] += lo16(U.x); acc[1] += hi16(U.x); \
                    acc[2] += lo16(U.y); acc[3] += hi16(U.y); \
                    acc[4] += lo16(U.z); acc[5] += hi16(U.z); \
                    acc[6] += lo16(U.w); acc[7] += hi16(U.w);
                ACC8(u0); ACC8(u1); ACC8(u2); ACC8(u3);
                #undef ACC8
            }
        } else {
            const float4* fq = (const float4*)feature;  // row = 32 float4
            for (int j = s; j < e; j += 8) {
                int j0 = j + g, j1 = j0 + 4;
                if (j0 < e) {
                    size_t b0 = (size_t)csr[j0] * 32 + c * 2;
                    float4 x = fq[b0], y = fq[b0 + 1];
                    acc[0] += x.x; acc[1] += x.y; acc[2] += x.z; acc[3] += x.w;
                    acc[4] += y.x; acc[5] += y.y; acc[6] += y.z; acc[7] += y.w;
                }
                if (j1 < e) {
                    size_t b1 = (size_t)csr[j1] * 32 + c * 2;
                    float4 x = fq[b1], y = fq[b1 + 1];
                    acc[0] += x.x; acc[1] += x.y; acc[2] += x.z; acc[3] += x.w;
                    acc[4] += y.x; acc[5] += y.y; acc[6] += y.z; acc[7] += y.w;
                }
            }
        }
    }
    // combine the 4 edge-slot partials (lanes g=0..3 share chunk c)
    #pragma unroll
    for (int t = 0; t < 8; ++t) {
        acc[t] += __shfl_xor(acc[t], 16);
        acc[t] += __shfl_xor(acc[t], 32);
    }
    float sc = 1.0f / (float)(degn > 1 ? degn : 1);
    if (g == 0) {
        uint4 o4;
        o4.x = (u32)f2bf(acc[0] * sc) | ((u32)f2bf(acc[1] * sc) << 16);
        o4.y = (u32)f2bf(acc[2] * sc) | ((u32)f2bf(acc[3] * sc) << 16);
        o4.z = (u32)f2bf(acc[4] * sc) | ((u32)f2bf(acc[5] * sc) << 16);
        o4.w = (u32)f2bf(acc[6] * sc) | ((u32)f2bf(acc[7] * sc) << 16);
        ((uint4*)(agg + (size_t)node * D_DIM))[c] = o4;
    }
}

// --- K6: h = agg @ W^T + b via bf16 MFMA, h written IN PLACE over agg -------
// Block = 64 rows x 128 cols, 4 waves, each wave one 16-row strip.
// fp32-W path: two MFMA passes with W split into bf16 hi + lo planes.
__global__ void k_gemm(u16* agg, const void* W, const void* bias,
                       float* colsum, float* colsq, const int* flag, int n) {
    __shared__ u16 sW[128 * 136];
    __shared__ float bsum[128], bsq[128];
    const int tid = threadIdx.x;
    const int rb = blockIdx.x * 64;
    const int bf = flag[0];
    const int w = tid >> 6;
    const int lane = tid & 63;
    const int g = lane >> 4, c = lane & 15;

    if (tid < 128) { bsum[tid] = 0.f; bsq[tid] = 0.f; }

    // A fragments: 4 x 16B per lane, reused across all 8 output tiles + passes
    bf16x8 afr[4];
    {
        const u16* arow = agg + (size_t)(rb + w * 16 + c) * D_DIM + g * 8;
        #pragma unroll
        for (int kt = 0; kt < 4; ++kt)
            afr[kt] = *(const bf16x8*)(arow + kt * 32);
    }

    f32x4 acc[8];
    #pragma unroll
    for (int ot = 0; ot < 8; ++ot) acc[ot] = (f32x4){0.f, 0.f, 0.f, 0.f};

    const int npass = bf ? 1 : 2;
    for (int pass = 0; pass < npass; ++pass) {
        if (bf) {
            #pragma unroll
            for (int i = 0; i < 8; ++i) {
                int e = (i * 256 + tid) * 8;
                int row = e >> 7, k = e & 127;
                *(uint4*)(&sW[row * 136 + k]) = *(const uint4*)((const u16*)W + e);
            }
        } else {
            const float* Wf = (const float*)W;
            #pragma unroll
            for (int i = 0; i < 8; ++i) {
                int e = (i * 256 + tid) * 8;
                int row = e >> 7, k = e & 127;
                float4 x = *(const float4*)(Wf + e);
                float4 y = *(const float4*)(Wf + e + 4);
                float v[8] = {x.x, x.y, x.z, x.w, y.x, y.y, y.z, y.w};
                u16 hb[8];
                #pragma unroll
                for (int j = 0; j < 8; ++j) {
                    u16 h = f2bf(v[j]);
                    if (pass == 1) h = f2bf(v[j] - bf2f(h));   // residual plane
                    hb[j] = h;
                }
                uint4 pk;
                pk.x = (u32)hb[0] | ((u32)hb[1] << 16);
                pk.y = (u32)hb[2] | ((u32)hb[3] << 16);
                pk.z = (u32)hb[4] | ((u32)hb[5] << 16);
                pk.w = (u32)hb[6] | ((u32)hb[7] << 16);
                *(uint4*)(&sW[row * 136 + k]) = pk;
            }
        }
        __syncthreads();
        #pragma unroll
        for (int ot = 0; ot < 8; ++ot) {
            const u16* wrow = &sW[(ot * 16 + c) * 136 + g * 8];
            #pragma unroll
            for (int kt = 0; kt < 4; ++kt) {
                bf16x8 bfr = *(const bf16x8*)(wrow + kt * 32);
                acc[ot] = __builtin_amdgcn_mfma_f32_16x16x32_bf16(
                    afr[kt], bfr, acc[ot], 0, 0, 0);
            }
        }
        if (pass + 1 < npass) __syncthreads();   // before restaging W plane
    }

    // Epilogue: bias, BN partial stats (rows<n only), packed bf16 store.
    // D layout: col = ot*16 + (lane&15), row-in-strip = (lane>>4)*4 + r.
    const int rowbase = rb + w * 16 + g * 4;
    #pragma unroll
    for (int ot = 0; ot < 8; ++ot) {
        const int o = ot * 16 + c;
        float bv = bf ? bf2f(((const u16*)bias)[o]) : ((const float*)bias)[o];
        float s = 0.f, q = 0.f;
        float hv[4];
        #pragma unroll
        for (int r = 0; r < 4; ++r) {
            float h = acc[ot][r] + bv;
            hv[r] = h;
            if (rowbase + r < n) { s += h; q += h * h; }
        }
        #pragma unroll
        for (int r = 0; r < 4; ++r) {
            float hp = __shfl_xor(hv[r], 1);       // neighbor col (o^1)
            if (!(lane & 1)) {
                u32 pk = (u32)f2bf(hv[r]) | ((u32)f2bf(hp) << 16);
                *(u32*)(agg + (size_t)(rowbase + r) * D_DIM + o) = pk;
            }
        }
        s += __shfl_xor(s, 16); s += __shfl_xor(s, 32);
        q += __shfl_xor(q, 16); q += __shfl_xor(q, 32);
        if (g == 0) { atomicAdd(&bsum[o], s); atomicAdd(&bsq[o], q); }
    }
    __syncthreads();
    if (tid < 128) {
        atomicAdd(&colsum[tid], bsum[tid]);
        atomicAdd(&colsq[tid], bsq[tid]);
    }
}

// --- K8: out = feature + relu(h*scale + shift); BN finalize folded in -------
__global__ void k_apply(const u16* h, const void* feature, const float* stats,
                        const void* gamma, const void* beta, void* outp,
                        const int* flag, int total8, float invn) {
    __shared__ float ssc[128], ssh[128];
    int tid = threadIdx.x;
    int bf = flag[0];
    if (tid < 128) {
        float mean = stats[tid] * invn;
        float var = stats[128 + tid] * invn - mean * mean;
        var = fmaxf(var, 0.f);
        float inv = rsqrtf(var + 1e-5f);
        float g = bf ? bf2f(((const u16*)gamma)[tid]) : ((const float*)gamma)[tid];
        float bb = bf ? bf2f(((const u16*)beta)[tid]) : ((const float*)beta)[tid];
        float sc = inv * g;
        ssc[tid] = sc;
        ssh[tid] = bb - mean * sc;
    }
    __syncthreads();
    int i = blockIdx.x * 256 + tid;
    if (i >= total8) return;
    size_t base = (size_t)i * 8;
    int c0 = (int)(base & (D_DIM - 1));
    uint4 h4 = ((const uint4*)h)[i];
    u32 hw[4] = {h4.x, h4.y, h4.z, h4.w};
    float hv[8];
    for (int j = 0; j < 4; ++j) { hv[2*j] = lo16(hw[j]); hv[2*j+1] = hi16(hw[j]); }
    float fv[8];
    if (bf) {
        uint4 f4 = ((const uint4*)feature)[i];
        u32 fw[4] = {f4.x, f4.y, f4.z, f4.w};
        for (int j = 0; j < 4; ++j) { fv[2*j] = lo16(fw[j]); fv[2*j+1] = hi16(fw[j]); }
    } else {
        float4 fa = ((const float4*)feature)[i * 2];
        float4 fb = ((const float4*)feature)[i * 2 + 1];
        fv[0]=fa.x; fv[1]=fa.y; fv[2]=fa.z; fv[3]=fa.w;
        fv[4]=fb.x; fv[5]=fb.y; fv[6]=fb.z; fv[7]=fb.w;
    }
    float ov[8];
    for (int j = 0; j < 8; ++j)
        ov[j] = fmaxf(hv[j] * ssc[c0 + j] + ssh[c0 + j], 0.f) + fv[j];
    if (bf) {
        uint4 o4;
        u32 ow[4];
        for (int j = 0; j < 4; ++j)
            ow[j] = (u32)f2bf(ov[2*j]) | ((u32)f2bf(ov[2*j+1]) << 16);
        o4.x = ow[0]; o4.y = ow[1]; o4.z = ow[2]; o4.w = ow[3];
        ((uint4*)outp)[i] = o4;
    } else {
        float4 oa, ob;
        oa.x=ov[0]; oa.y=ov[1]; oa.z=ov[2]; oa.w=ov[3];
        ob.x=ov[4]; ob.y=ov[5]; ob.z=ov[6]; ob.w=ov[7];
        ((float4*)outp)[i * 2] = oa;
        ((float4*)outp)[i * 2 + 1] = ob;
    }
}

static inline size_t al256s(size_t x) { return (x + 255) & ~(size_t)255; }
static inline int gmax1(int x) { return x > 0 ? x : 1; }

extern "C" void kernel_launch(void* const* d_in, const int* in_sizes, int n_in,
                              void* d_out, int out_size, void* d_ws, size_t ws_size,
                              hipStream_t stream) {
    const void* feature = d_in[0];
    const int*  src     = (const int*)d_in[1];
    const int*  dst     = (const int*)d_in[2];
    const void* W       = d_in[3];
    const void* bias    = d_in[4];
    const void* gamma   = d_in[5];
    const void* beta    = d_in[6];

    const int N = in_sizes[0] / D_DIM;
    const int E = in_sizes[1];
    const int Npad = (N + 63) & ~63;
    const int nblk = (N + CHUNK - 1) / CHUNK;      // scan blocks
    const int nper = (N + NPART - 1) / NPART;      // nodes per XCD partition

    char* p = (char*)d_ws;
    size_t o = 0;
    int*   flag   = (int*)(p + o);      o += 256;
    int*   deg    = (int*)(p + o);      o += (size_t)N * 4;
    float* stats  = (float*)(p + o);    o += 256 * 4;           // sum[128],sq[128]
    const int zero_words = N + 256;                              // deg+stats contiguous
    o = al256s(o);
    int*   bsums  = (int*)(p + o);      o += al256s(((size_t)nblk + 8) * 4);
    int*   offs   = (int*)(p + o);      o += al256s(((size_t)N + 8) * 4);
    int*   csr    = (int*)(p + o);      o += al256s((size_t)E * 4);
    u16*   agg    = (u16*)(p + o);      o += al256s((size_t)Npad * D_DIM * 2);
    int*   rank   = (int*)agg;   // aliased: rank (E ints) dies before k_aggregate
                                 // writes agg; Npad*256B >= E*4B here
    (void)ws_size; (void)n_in; (void)out_size;

    int eb = gmax1((E + 255) / 256);
    int total8 = N * D_DIM / 8;
    int sblocks = gmax1(((E + SCHUNK - 1) / SCHUNK) * NPART);

    GCNLayer_76647986365164_kernel<<<gmax1((zero_words + 255) / 256), 256, 0, stream>>>(
        deg, zero_words, (const u32*)feature, flag);
    k_deg<<<eb, 256, 0, stream>>>(dst, deg, rank, E);
    k_scan_local<<<gmax1(nblk), 256, 0, stream>>>(deg, offs, bsums, N);
    k_scan_add<<<gmax1(nblk), 256, 0, stream>>>(offs, bsums, N, nblk);
    k_scatter<<<sblocks, 256, 0, stream>>>(src, dst, rank, offs, csr, E, nper);
    k_aggregate<<<gmax1(Npad / 4), 256, 0, stream>>>(feature, offs, csr, agg, flag, N, Npad);
    k_gemm<<<gmax1(Npad / 64), 256, 0, stream>>>(agg, W, bias, stats, stats + 128, flag, N);
    k_apply<<<gmax1((total8 + 255) / 256), 256, 0, stream>>>(
        agg, feature, stats, gamma, beta, d_out, flag, total8, 1.0f / (float)N);
}

// Round 3
// 313.992 us; speedup vs baseline: 1.2977x; 1.0311x over previous
//
#include <hip/hip_runtime.h>

typedef unsigned short u16;
typedef unsigned int u32;

#define D_DIM 128
#define CHUNK 4096    // elements scanned per block (256 threads x 16)
#define SCHUNK 4096   // edges per scatter stripe
#define NPART 8       // XCD count

typedef __attribute__((ext_vector_type(8))) short bf16x8;
typedef __attribute__((ext_vector_type(4))) float f32x4;

__device__ __forceinline__ float bf2f(u16 h) {
    u32 u = ((u32)h) << 16;
    return __uint_as_float(u);
}
__device__ __forceinline__ u16 f2bf(float f) {
    u32 u = __float_as_uint(f);
    u32 r = (u >> 16) & 1u;
    u += 0x7fffu + r;                 // round-to-nearest-even
    return (u16)(u >> 16);
}
__device__ __forceinline__ float lo16(u32 u) { return bf2f((u16)(u & 0xffffu)); }
__device__ __forceinline__ float hi16(u32 u) { return bf2f((u16)(u >> 16)); }

// --- K1: zero scratch words + dtype detect (merged; harness symbol kept) ----
__global__ void GCNLayer_76647986365164_kernel(int* p, int nwords,
                                               const u32* w, int* flag) {
    int i = blockIdx.x * blockDim.x + threadIdx.x;
    if (i < nwords) p[i] = 0;
    if (blockIdx.x == 0) {
        __shared__ int cnt;
        if (threadIdx.x == 0) cnt = 0;
        __syncthreads();
        int c = 0;
        for (int j = 0; j < 4; ++j) {
            u32 x = w[threadIdx.x * 4 + j];
            u32 e = (x >> 7) & 0xFFu;
            if (e >= 100u && e <= 140u) c++;
        }
        atomicAdd(&cnt, c);
        __syncthreads();
        if (threadIdx.x == 0) flag[0] = (cnt >= 700) ? 1 : 0;
    }
}

// --- K1b: fp32 feature -> bf16 copy (skipped when input already bf16) -------
// The copy lands in d_out, which is dead until k_apply overwrites it.
__global__ void k_tobf(const float* __restrict__ f, u16* __restrict__ fb,
                       const int* __restrict__ flag, int total8) {
    if (flag[0]) return;                 // input already bf16
    int i = blockIdx.x * 256 + threadIdx.x;
    if (i >= total8) return;
    float4 a = ((const float4*)f)[i * 2];
    float4 b = ((const float4*)f)[i * 2 + 1];
    uint4 o;
    o.x = (u32)f2bf(a.x) | ((u32)f2bf(a.y) << 16);
    o.y = (u32)f2bf(a.z) | ((u32)f2bf(a.w) << 16);
    o.z = (u32)f2bf(b.x) | ((u32)f2bf(b.y) << 16);
    o.w = (u32)f2bf(b.z) | ((u32)f2bf(b.w) << 16);
    ((uint4*)fb)[i] = o;
}

// --- K2: in-degree count + per-edge bucket rank -----------------------------
__global__ void k_deg(const int* __restrict__ dst, int* __restrict__ deg,
                      int* __restrict__ rank, int E) {
    int i = blockIdx.x * blockDim.x + threadIdx.x;
    if (i < E) rank[i] = atomicAdd(&deg[dst[i]], 1);
}

// --- K3a: block-local exclusive scan (multi-block; LDS Hillis-Steele) -------
__global__ void k_scan_local(const int* deg, int* offs, int* bsums, int n) {
    __shared__ int tsum[256];
    const int tid = threadIdx.x;
    const int base = blockIdx.x * CHUNK + tid * 16;
    int v[16];
    int run = 0;
    for (int j = 0; j < 16; ++j) {
        int idx = base + j;
        v[j] = (idx < n) ? deg[idx] : 0;
        run += v[j];
    }
    tsum[tid] = run;
    __syncthreads();
    for (int off = 1; off < 256; off <<= 1) {      // inclusive scan of thread sums
        int val = tsum[tid];
        int add = (tid >= off) ? tsum[tid - off] : 0;
        __syncthreads();
        tsum[tid] = val + add;
        __syncthreads();
    }
    int acc = tsum[tid] - run;                     // exclusive start (local)
    for (int j = 0; j < 16; ++j) {
        int idx = base + j;
        if (idx < n) offs[idx] = acc;
        acc += v[j];
    }
    if (tid == 255) bsums[blockIdx.x] = tsum[255];
}

// --- K3b: add scanned block totals; emit final offs -------------------------
__global__ void k_scan_add(int* offs, const int* bsums, int n, int nblk) {
    __shared__ int carry_s;
    const int tid = threadIdx.x;
    const int b = blockIdx.x;
    if (tid == 0) {
        int c = 0;
        for (int i = 0; i < b; ++i) c += bsums[i];
        carry_s = c;
        if (b == nblk - 1) offs[n] = c + bsums[b];   // total == E
    }
    __syncthreads();
    const int carry = carry_s;
    const int base = b * CHUNK + tid * 16;
    for (int j = 0; j < 16; ++j) {
        int idx = base + j;
        if (idx < n) offs[idx] += carry;
    }
}

// --- K4: scatter edges into CSR buckets, XCD-partitioned, atomic-free -------
__global__ void k_scatter(const int* __restrict__ src, const int* __restrict__ dst,
                          const int* __restrict__ rank, const int* __restrict__ offs,
                          int* __restrict__ csr, int E, int nper) {
    const int pr = blockIdx.x & (NPART - 1);
    const int s  = blockIdx.x >> 3;
    const int lo = pr * nper;
    const int hi = lo + nper;
    const int base = s * SCHUNK;
    int end = base + SCHUNK;
    if (end > E) end = E;
    for (int i = base + (int)threadIdx.x; i < end; i += 256) {
        int d = dst[i];
        if (d >= lo && d < hi) {
            csr[offs[d] + rank[i]] = src[i];
        }
    }
}

// --- K5: gather-reduce mean aggregation, one wave per node ------------------
// Always gathers bf16 rows (256B): original buffer when input is bf16, the
// k_tobf copy otherwise (halves gather bytes vs fp32 512B rows; R2 showed
// FETCH 237MB at 3.1 TB/s L2-miss delivery was the bound).
__global__ void k_aggregate(const void* feature, const u16* __restrict__ fcopy,
                            const int* offs, const int* csr, u16* agg,
                            const int* flag, int n, int npad) {
    int node = blockIdx.x * 4 + (threadIdx.x >> 6);
    int lane = threadIdx.x & 63;
    if (node >= npad) return;
    const int g = lane >> 4;       // edge sub-slot 0..3
    const int c = lane & 15;       // 16B chunk (8 bf16 cols) within row
    const u16* fb = flag[0] ? (const u16*)feature : fcopy;
    float acc[8];
    #pragma unroll
    for (int t = 0; t < 8; ++t) acc[t] = 0.f;
    int degn = 0;
    if (node < n) {
        int s = offs[node], e = offs[node + 1];
        degn = e - s;
        const uint4* fq = (const uint4*)fb;   // row = 16 uint4
        for (int j = s; j < e; j += 16) {
            int j0 = j + g, j1 = j0 + 4, j2 = j0 + 8, j3 = j0 + 12;
            uint4 u0 = {0,0,0,0}, u1 = {0,0,0,0}, u2 = {0,0,0,0}, u3 = {0,0,0,0};
            if (j0 < e) u0 = fq[(size_t)csr[j0] * 16 + c];
            if (j1 < e) u1 = fq[(size_t)csr[j1] * 16 + c];
            if (j2 < e) u2 = fq[(size_t)csr[j2] * 16 + c];
            if (j3 < e) u3 = fq[(size_t)csr[j3] * 16 + c];
            #define ACC8(U) \
                acc[0] += lo16(U.x); acc[1] += hi16(U.x); \
                acc[2] += lo16(U.y); acc[3] += hi16(U.y); \
                acc[4] += lo16(U.z); acc[5] += hi16(U.z); \
                acc[6] += lo16(U.w); acc[7] += hi16(U.w);
            ACC8(u0); ACC8(u1); ACC8(u2); ACC8(u3);
            #undef ACC8
        }
    }
    // combine the 4 edge-slot partials (lanes g=0..3 share chunk c)
    #pragma unroll
    for (int t = 0; t < 8; ++t) {
        acc[t] += __shfl_xor(acc[t], 16);
        acc[t] += __shfl_xor(acc[t], 32);
    }
    float sc = 1.0f / (float)(degn > 1 ? degn : 1);
    if (g == 0) {
        uint4 o4;
        o4.x = (u32)f2bf(acc[0] * sc) | ((u32)f2bf(acc[1] * sc) << 16);
        o4.y = (u32)f2bf(acc[2] * sc) | ((u32)f2bf(acc[3] * sc) << 16);
        o4.z = (u32)f2bf(acc[4] * sc) | ((u32)f2bf(acc[5] * sc) << 16);
        o4.w = (u32)f2bf(acc[6] * sc) | ((u32)f2bf(acc[7] * sc) << 16);
        ((uint4*)(agg + (size_t)node * D_DIM))[c] = o4;
    }
}

// --- K6: h = agg @ W^T + b via bf16 MFMA, h written IN PLACE over agg -------
// Changes vs R2 (83us, MfmaUtil 3%, VALUBusy 14% -> pure serialization):
//  1. NO global atomics: per-block BN partials written coalesced to
//     partials[block][256]; k_redstats reduces them (was 400K contended
//     device atomics on 16 cache lines = ~80us of serialization).
//  2. W staged in FRAGMENT order sWf[(ot*4+kt)*64+lane] so LDS writes and
//     reads are lane-consecutive b128 (was 8-way bank conflict, 1.6M cycles).
__global__ void k_gemm(u16* agg, const void* W, const void* bias,
                       float* __restrict__ partials, const int* flag, int n) {
    __shared__ u16 sWf[2048 * 8];          // 32 KB, 16B per (frag,lane)
    __shared__ float bsum[128], bsq[128];
    const int tid = threadIdx.x;
    const int rb = blockIdx.x * 64;
    const int bf = flag[0];
    const int w = tid >> 6;
    const int lane = tid & 63;
    const int g = lane >> 4, c = lane & 15;

    if (tid < 128) { bsum[tid] = 0.f; bsq[tid] = 0.f; }

    // A fragments: 4 x 16B per lane, reused across all 8 output tiles + passes
    bf16x8 afr[4];
    {
        const u16* arow = agg + (size_t)(rb + w * 16 + c) * D_DIM + g * 8;
        #pragma unroll
        for (int kt = 0; kt < 4; ++kt)
            afr[kt] = *(const bf16x8*)(arow + kt * 32);
    }

    f32x4 acc[8];
    #pragma unroll
    for (int ot = 0; ot < 8; ++ot) acc[ot] = (f32x4){0.f, 0.f, 0.f, 0.f};

    const int npass = bf ? 1 : 2;
    for (int pass = 0; pass < npass; ++pass) {
        // stage W in fragment order: unit idx -> frag=idx>>6, dlane=idx&63
        #pragma unroll
        for (int i = 0; i < 8; ++i) {
            int idx = i * 256 + tid;
            int frag = idx >> 6, dl = idx & 63;
            int ot = frag >> 2, kt = frag & 3;
            int dg = dl >> 4, dc = dl & 15;
            int row = ot * 16 + dc, col = kt * 32 + dg * 8;
            if (bf) {
                *(uint4*)(&sWf[idx * 8]) =
                    *(const uint4*)((const u16*)W + row * 128 + col);
            } else {
                const float* Wf = (const float*)W;
                float4 x = *(const float4*)(Wf + row * 128 + col);
                float4 y = *(const float4*)(Wf + row * 128 + col + 4);
                float v[8] = {x.x, x.y, x.z, x.w, y.x, y.y, y.z, y.w};
                u16 hb[8];
                #pragma unroll
                for (int j = 0; j < 8; ++j) {
                    u16 h = f2bf(v[j]);
                    if (pass == 1) h = f2bf(v[j] - bf2f(h));   // residual plane
                    hb[j] = h;
                }
                uint4 pk;
                pk.x = (u32)hb[0] | ((u32)hb[1] << 16);
                pk.y = (u32)hb[2] | ((u32)hb[3] << 16);
                pk.z = (u32)hb[4] | ((u32)hb[5] << 16);
                pk.w = (u32)hb[6] | ((u32)hb[7] << 16);
                *(uint4*)(&sWf[idx * 8]) = pk;
            }
        }
        __syncthreads();
        #pragma unroll
        for (int ot = 0; ot < 8; ++ot) {
            #pragma unroll
            for (int kt = 0; kt < 4; ++kt) {
                bf16x8 bfr = *(const bf16x8*)(&sWf[((ot * 4 + kt) * 64 + lane) * 8]);
                acc[ot] = __builtin_amdgcn_mfma_f32_16x16x32_bf16(
                    afr[kt], bfr, acc[ot], 0, 0, 0);
            }
        }
        if (pass + 1 < npass) __syncthreads();   // before restaging W plane
    }

    // Epilogue: bias, BN partial stats (rows<n only), packed bf16 store.
    // D layout: col = ot*16 + (lane&15), row-in-strip = (lane>>4)*4 + r.
    const int rowbase = rb + w * 16 + g * 4;
    #pragma unroll
    for (int ot = 0; ot < 8; ++ot) {
        const int o = ot * 16 + c;
        float bv = bf ? bf2f(((const u16*)bias)[o]) : ((const float*)bias)[o];
        float s = 0.f, q = 0.f;
        float hv[4];
        #pragma unroll
        for (int r = 0; r < 4; ++r) {
            float h = acc[ot][r] + bv;
            hv[r] = h;
            if (rowbase + r < n) { s += h; q += h * h; }
        }
        #pragma unroll
        for (int r = 0; r < 4; ++r) {
            float hp = __shfl_xor(hv[r], 1);       // neighbor col (o^1)
            if (!(lane & 1)) {
                u32 pk = (u32)f2bf(hv[r]) | ((u32)f2bf(hp) << 16);
                *(u32*)(agg + (size_t)(rowbase + r) * D_DIM + o) = pk;
            }
        }
        s += __shfl_xor(s, 16); s += __shfl_xor(s, 32);
        q += __shfl_xor(q, 16); q += __shfl_xor(q, 32);
        if (g == 0) { atomicAdd(&bsum[o], s); atomicAdd(&bsq[o], q); }
    }
    __syncthreads();
    // coalesced per-block partials, no global atomics
    partials[(size_t)blockIdx.x * 256 + tid] =
        (tid < 128) ? bsum[tid] : bsq[tid - 128];
}

// --- K6b: reduce per-block BN partials into stats (8K atomics total) --------
__global__ void k_redstats(const float* __restrict__ partials,
                           float* __restrict__ stats, int nb) {
    const int tid = threadIdx.x;
    float acc = 0.f;
    for (int r = blockIdx.x; r < nb; r += gridDim.x)
        acc += partials[(size_t)r * 256 + tid];
    atomicAdd(&stats[tid], acc);
}

// --- K8: out = feature + relu(h*scale + shift); BN finalize folded in -------
__global__ void k_apply(const u16* h, const void* feature, const float* stats,
                        const void* gamma, const void* beta, void* outp,
                        const int* flag, int total8, float invn) {
    __shared__ float ssc[128], ssh[128];
    int tid = threadIdx.x;
    int bf = flag[0];
    if (tid < 128) {
        float mean = stats[tid] * invn;
        float var = stats[128 + tid] * invn - mean * mean;
        var = fmaxf(var, 0.f);
        float inv = rsqrtf(var + 1e-5f);
        float g = bf ? bf2f(((const u16*)gamma)[tid]) : ((const float*)gamma)[tid];
        float bb = bf ? bf2f(((const u16*)beta)[tid]) : ((const float*)beta)[tid];
        float sc = inv * g;
        ssc[tid] = sc;
        ssh[tid] = bb - mean * sc;
    }
    __syncthreads();
    int i = blockIdx.x * 256 + tid;
    if (i >= total8) return;
    size_t base = (size_t)i * 8;
    int c0 = (int)(base & (D_DIM - 1));
    uint4 h4 = ((const uint4*)h)[i];
    u32 hw[4] = {h4.x, h4.y, h4.z, h4.w};
    float hv[8];
    for (int j = 0; j < 4; ++j) { hv[2*j] = lo16(hw[j]); hv[2*j+1] = hi16(hw[j]); }
    float fv[8];
    if (bf) {
        uint4 f4 = ((const uint4*)feature)[i];
        u32 fw[4] = {f4.x, f4.y, f4.z, f4.w};
        for (int j = 0; j < 4; ++j) { fv[2*j] = lo16(fw[j]); fv[2*j+1] = hi16(fw[j]); }
    } else {
        float4 fa = ((const float4*)feature)[i * 2];
        float4 fb = ((const float4*)feature)[i * 2 + 1];
        fv[0]=fa.x; fv[1]=fa.y; fv[2]=fa.z; fv[3]=fa.w;
        fv[4]=fb.x; fv[5]=fb.y; fv[6]=fb.z; fv[7]=fb.w;
    }
    float ov[8];
    for (int j = 0; j < 8; ++j)
        ov[j] = fmaxf(hv[j] * ssc[c0 + j] + ssh[c0 + j], 0.f) + fv[j];
    if (bf) {
        uint4 o4;
        u32 ow[4];
        for (int j = 0; j < 4; ++j)
            ow[j] = (u32)f2bf(ov[2*j]) | ((u32)f2bf(ov[2*j+1]) << 16);
        o4.x = ow[0]; o4.y = ow[1]; o4.z = ow[2]; o4.w = ow[3];
        ((uint4*)outp)[i] = o4;
    } else {
        float4 oa, ob;
        oa.x=ov[0]; oa.y=ov[1]; oa.z=ov[2]; oa.w=ov[3];
        ob.x=ov[4]; ob.y=ov[5]; ob.z=ov[6]; ob.w=ov[7];
        ((float4*)outp)[i * 2] = oa;
        ((float4*)outp)[i * 2 + 1] = ob;
    }
}

static inline size_t al256s(size_t x) { return (x + 255) & ~(size_t)255; }
static inline int gmax1(int x) { return x > 0 ? x : 1; }

extern "C" void kernel_launch(void* const* d_in, const int* in_sizes, int n_in,
                              void* d_out, int out_size, void* d_ws, size_t ws_size,
                              hipStream_t stream) {
    const void* feature = d_in[0];
    const int*  src     = (const int*)d_in[1];
    const int*  dst     = (const int*)d_in[2];
    const void* W       = d_in[3];
    const void* bias    = d_in[4];
    const void* gamma   = d_in[5];
    const void* beta    = d_in[6];

    const int N = in_sizes[0] / D_DIM;
    const int E = in_sizes[1];
    const int Npad = (N + 63) & ~63;
    const int nblk = (N + CHUNK - 1) / CHUNK;      // scan blocks
    const int nper = (N + NPART - 1) / NPART;      // nodes per XCD partition
    const int gb   = Npad / 64;                    // gemm blocks

    char* p = (char*)d_ws;
    size_t o = 0;
    int*   flag   = (int*)(p + o);      o += 256;
    int*   deg    = (int*)(p + o);      o += (size_t)N * 4;
    float* stats  = (float*)(p + o);    o += 256 * 4;           // sum[128],sq[128]
    const int zero_words = N + 256;                              // deg+stats contiguous
    o = al256s(o);
    int*   bsums  = (int*)(p + o);      o += al256s(((size_t)nblk + 8) * 4);
    int*   offs   = (int*)(p + o);      o += al256s(((size_t)N + 8) * 4);
    int*   csr    = (int*)(p + o);      o += al256s((size_t)E * 4);
    float* parts  = (float*)(p + o);    o += al256s((size_t)gb * 256 * 4);
    u16*   agg    = (u16*)(p + o);      o += al256s((size_t)Npad * D_DIM * 2);
    int*   rank   = (int*)agg;   // aliased: rank (E ints) dies before k_aggregate
                                 // writes agg; Npad*256B >= E*4B here
    u16*   fbf    = (u16*)d_out; // bf16 feature copy; dead before k_apply writes
    (void)ws_size; (void)n_in; (void)out_size;

    int eb = gmax1((E + 255) / 256);
    int total8 = N * D_DIM / 8;
    int sblocks = gmax1(((E + SCHUNK - 1) / SCHUNK) * NPART);

    GCNLayer_76647986365164_kernel<<<gmax1((zero_words + 255) / 256), 256, 0, stream>>>(
        deg, zero_words, (const u32*)feature, flag);
    k_tobf<<<gmax1((total8 + 255) / 256), 256, 0, stream>>>(
        (const float*)feature, fbf, flag, total8);
    k_deg<<<eb, 256, 0, stream>>>(dst, deg, rank, E);
    k_scan_local<<<gmax1(nblk), 256, 0, stream>>>(deg, offs, bsums, N);
    k_scan_add<<<gmax1(nblk), 256, 0, stream>>>(offs, bsums, N, nblk);
    k_scatter<<<sblocks, 256, 0, stream>>>(src, dst, rank, offs, csr, E, nper);
    k_aggregate<<<gmax1(Npad / 4), 256, 0, stream>>>(
        feature, fbf, offs, csr, agg, flag, N, Npad);
    k_gemm<<<gmax1(gb), 256, 0, stream>>>(agg, W, bias, parts, flag, N);
    k_redstats<<<32, 256, 0, stream>>>(parts, stats, gb);
    k_apply<<<gmax1((total8 + 255) / 256), 256, 0, stream>>>(
        agg, feature, stats, gamma, beta, d_out, flag, total8, 1.0f / (float)N);
}